// Round 1
// baseline (210.317 us; speedup 1.0000x reference)
//
#include <hip/hip_runtime.h>

// YOLO-style loss on MI355X.
// pred:      [B, 8, 8, 8] f32   (B = 65536)
// label_rc:  [B, L, 2]    i32   (L = 16)
// label_box: [B, L, 3]    f32
// out:       [1] f32 scalar = (coord_loss + cond_loss) / B
//
// Strategy: one 64-lane wave per batch. Lane i owns grid cell i (r=i>>3, c=i&7),
// holding its 8 pred floats in registers (two float4 loads, fully coalesced at
// wave granularity). The per-label gather of the responsible cell is done with
// __shfl from the owning lane (no second global read of pred). obj_mask is
// computed by broadcasting each label's cell index with __shfl and comparing
// against the lane id (duplicate labels collapse via OR, matching .set(1.0)).

static constexpr float LAMBDA_COORD = 5.0f;
static constexpr float LAMBDA_NOOBJ = 0.5f;
static constexpr float EPS_F = 1e-9f;

__device__ __forceinline__ float bbox_iou(float px, float py, float pr,
                                          float gx, float gy, float gr) {
    float l1 = px - pr, r1 = px + pr, t1 = py - pr, b1 = py + pr;
    float l2 = gx - gr, r2 = gx + gr, t2 = gy - gr, b2 = gy + gr;
    float iw = fmaxf(fminf(r1, r2) - fmaxf(l1, l2), 0.0f);
    float ih = fmaxf(fminf(b1, b2) - fmaxf(t1, t2), 0.0f);
    float inter = iw * ih;
    float a1 = (r1 - l1) * (b1 - t1);
    float a2 = (r2 - l2) * (b2 - t2);
    return inter / (a1 + a2 - inter + EPS_F);
}

__global__ void zero_out_kernel(float* __restrict__ out) { *out = 0.0f; }

__global__ __launch_bounds__(256) void yolo_loss_kernel(
    const float* __restrict__ pred,
    const int*   __restrict__ label_rc,
    const float* __restrict__ label_box,
    float* __restrict__ out,
    int B, int L, float invB)
{
    const int lane    = threadIdx.x & 63;
    const int wave_ib = threadIdx.x >> 6;   // wave within block (0..3)
    const int wave    = blockIdx.x * (blockDim.x >> 6) + wave_ib;
    const int nwaves  = gridDim.x * (blockDim.x >> 6);

    float acc = 0.0f;

    for (int b = wave; b < B; b += nwaves) {
        // ---- load this lane's cell: 8 contiguous floats, 16B-aligned ----
        const float* cell_ptr = pred + ((size_t)b << 9) + ((size_t)lane << 3);
        float4 q0 = *(const float4*)(cell_ptr);      // p0..p3
        float4 q1 = *(const float4*)(cell_ptr + 4);  // p4..p7

        // ---- lanes < L load their label ----
        int   cell = -1;                 // -1 => no label on this lane
        float gx = 0.f, gy = 0.f, gr = 0.f;
        if (lane < L) {
            const int2 rc = *(const int2*)(label_rc + ((size_t)b * L + lane) * 2);
            cell = rc.x * 8 + rc.y;      // responsible cell linear index (0..63)
            const float* lb = label_box + ((size_t)b * L + lane) * 3;
            gx = lb[0]; gy = lb[1]; gr = lb[2];
        }

        // ---- obj mask: is my cell referenced by any label? ----
        bool labeled = false;
        #pragma unroll
        for (int l = 0; l < 16; ++l) {
            if (l < L) labeled |= (__shfl(cell, l) == lane);
        }

        // ---- gather responsible cell's 8 pred values via cross-lane ----
        int src = (cell < 0) ? 0 : cell;
        float p0 = __shfl(q0.x, src);
        float p1 = __shfl(q0.y, src);
        float p2 = __shfl(q0.z, src);
        float p3 = __shfl(q0.w, src);
        float p4 = __shfl(q1.x, src);
        float p5 = __shfl(q1.y, src);
        float p6 = __shfl(q1.z, src);
        float p7 = __shfl(q1.w, src);

        // ---- noobj term for my cell (all 64 lanes) ----
        float contrib = labeled ? 0.0f
                      : LAMBDA_NOOBJ * (q0.w * q0.w + q1.w * q1.w);

        // ---- per-label loss (lanes < L) ----
        if (lane < L) {
            float iou1 = bbox_iou(p0, p1, p2, gx, gy, gr);
            float iou2 = bbox_iou(p4, p5, p6, gx, gy, gr);
            bool  sw   = iou2 > iou1;
            float cx      = sw ? p4 : p0;
            float cy      = sw ? p5 : p1;
            float cr      = sw ? p6 : p2;
            float conf    = sw ? p7 : p3;
            float un_conf = sw ? p3 : p7;
            float bigger  = sw ? iou2 : iou1;
            float smaller = sw ? iou1 : iou2;
            float dx = cx - gx, dy = cy - gy, dr = cr - gr;
            contrib += LAMBDA_COORD * (dx * dx + dy * dy + dr * dr);
            float d1 = bigger - conf;
            float d2 = smaller - un_conf;
            contrib += d1 * d1 + LAMBDA_NOOBJ * (d2 * d2);
        }

        acc += contrib;
    }

    // ---- wave reduction (64 lanes) ----
    #pragma unroll
    for (int off = 32; off > 0; off >>= 1)
        acc += __shfl_xor(acc, off);

    // ---- block reduction (4 waves) + one atomic per block ----
    __shared__ float wsum[4];
    if (lane == 0) wsum[wave_ib] = acc;
    __syncthreads();
    if (threadIdx.x == 0) {
        float s = wsum[0] + wsum[1] + wsum[2] + wsum[3];
        atomicAdd(out, s * invB);
    }
}

extern "C" void kernel_launch(void* const* d_in, const int* in_sizes, int n_in,
                              void* d_out, int out_size, void* d_ws, size_t ws_size,
                              hipStream_t stream) {
    const float* pred      = (const float*)d_in[0];
    const int*   label_rc  = (const int*)d_in[1];
    const float* label_box = (const float*)d_in[2];
    float*       out       = (float*)d_out;

    const int B = in_sizes[0] / 512;          // G*G*C = 8*8*8
    const int L = in_sizes[1] / (B * 2);      // labels per batch (16)
    const float invB = 1.0f / (float)B;

    // d_out is re-poisoned (0xAA) before every timed replay: zero it ourselves.
    zero_out_kernel<<<1, 1, 0, stream>>>(out);

    const int threads = 256;
    const int blocks  = 1024;                 // 4096 waves, 16 batches each
    yolo_loss_kernel<<<blocks, threads, 0, stream>>>(
        pred, label_rc, label_box, out, B, L, invB);
}

// Round 2
// 207.776 us; speedup vs baseline: 1.0122x; 1.0122x over previous
//
#include <hip/hip_runtime.h>

// YOLO-style loss on MI355X — round 2.
// pred:      [B, 8, 8, 8] f32   (B = 65536)
// label_rc:  [B, L, 2]    i32   (L = 16)
// label_box: [B, L, 3]    f32
// out:       [1] f32 scalar = (coord_loss + cond_loss) / B
//
// R2 changes vs R1 (210 us, latency-bound):
//  - one wave per batch (65536 waves, 32 waves/CU occupancy) instead of
//    4096 waves x 16 serial iterations -> 8x more latency hiding, single
//    load round-trip per wave.
//  - atomic-free two-stage reduction: block partials -> d_ws, then a
//    1-block reduce kernel. Removes 1024 same-address fp32 atomics and the
//    zero-out kernel.

static constexpr float LAMBDA_COORD = 5.0f;
static constexpr float LAMBDA_NOOBJ = 0.5f;
static constexpr float EPS_F = 1e-9f;

__device__ __forceinline__ float bbox_iou(float px, float py, float pr,
                                          float gx, float gy, float gr) {
    float l1 = px - pr, r1 = px + pr, t1 = py - pr, b1 = py + pr;
    float l2 = gx - gr, r2 = gx + gr, t2 = gy - gr, b2 = gy + gr;
    float iw = fmaxf(fminf(r1, r2) - fmaxf(l1, l2), 0.0f);
    float ih = fmaxf(fminf(b1, b2) - fmaxf(t1, t2), 0.0f);
    float inter = iw * ih;
    float a1 = (r1 - l1) * (b1 - t1);
    float a2 = (r2 - l2) * (b2 - t2);
    return inter / (a1 + a2 - inter + EPS_F);
}

__global__ __launch_bounds__(256) void yolo_loss_kernel(
    const float* __restrict__ pred,
    const int*   __restrict__ label_rc,
    const float* __restrict__ label_box,
    float* __restrict__ partials,
    int B, int L)
{
    const int lane    = threadIdx.x & 63;
    const int wave_ib = threadIdx.x >> 6;        // 0..3
    const int b       = blockIdx.x * 4 + wave_ib; // one wave per batch

    float contrib = 0.0f;

    if (b < B) {
        // ---- this lane's cell: 8 contiguous floats (two float4) ----
        const float* cell_ptr = pred + ((size_t)b << 9) + ((size_t)lane << 3);
        float4 q0 = *(const float4*)(cell_ptr);      // p0..p3
        float4 q1 = *(const float4*)(cell_ptr + 4);  // p4..p7

        // ---- lanes < L load their label ----
        int   cell = -1;
        float gx = 0.f, gy = 0.f, gr = 0.f;
        if (lane < L) {
            const int2 rc = *(const int2*)(label_rc + ((size_t)b * L + lane) * 2);
            cell = rc.x * 8 + rc.y;
            const float* lb = label_box + ((size_t)b * L + lane) * 3;
            gx = lb[0]; gy = lb[1]; gr = lb[2];
        }

        // ---- obj mask: is my cell referenced by any label? ----
        bool labeled = false;
        #pragma unroll
        for (int l = 0; l < 16; ++l) {
            if (l < L) labeled |= (__shfl(cell, l) == lane);
        }

        // ---- gather responsible cell's 8 pred values via cross-lane ----
        int src = (cell < 0) ? 0 : cell;
        float p0 = __shfl(q0.x, src);
        float p1 = __shfl(q0.y, src);
        float p2 = __shfl(q0.z, src);
        float p3 = __shfl(q0.w, src);
        float p4 = __shfl(q1.x, src);
        float p5 = __shfl(q1.y, src);
        float p6 = __shfl(q1.z, src);
        float p7 = __shfl(q1.w, src);

        // ---- noobj term for my cell (all 64 lanes) ----
        contrib = labeled ? 0.0f
                : LAMBDA_NOOBJ * (q0.w * q0.w + q1.w * q1.w);

        // ---- per-label loss (lanes < L) ----
        if (lane < L) {
            float iou1 = bbox_iou(p0, p1, p2, gx, gy, gr);
            float iou2 = bbox_iou(p4, p5, p6, gx, gy, gr);
            bool  sw   = iou2 > iou1;
            float cx      = sw ? p4 : p0;
            float cy      = sw ? p5 : p1;
            float cr      = sw ? p6 : p2;
            float conf    = sw ? p7 : p3;
            float un_conf = sw ? p3 : p7;
            float bigger  = sw ? iou2 : iou1;
            float smaller = sw ? iou1 : iou2;
            float dx = cx - gx, dy = cy - gy, dr = cr - gr;
            contrib += LAMBDA_COORD * (dx * dx + dy * dy + dr * dr);
            float d1 = bigger - conf;
            float d2 = smaller - un_conf;
            contrib += d1 * d1 + LAMBDA_NOOBJ * (d2 * d2);
        }
    }

    // ---- wave reduction ----
    #pragma unroll
    for (int off = 32; off > 0; off >>= 1)
        contrib += __shfl_xor(contrib, off);

    // ---- block reduction (4 waves) -> one partial per block ----
    __shared__ float wsum[4];
    if (lane == 0) wsum[wave_ib] = contrib;
    __syncthreads();
    if (threadIdx.x == 0)
        partials[blockIdx.x] = wsum[0] + wsum[1] + wsum[2] + wsum[3];
}

__global__ __launch_bounds__(256) void reduce_kernel(
    const float* __restrict__ partials, float* __restrict__ out,
    int n4, float invB)
{
    const float4* p4 = (const float4*)partials;
    float4 s4 = make_float4(0.f, 0.f, 0.f, 0.f);
    for (int i = threadIdx.x; i < n4; i += 256) {
        float4 v = p4[i];
        s4.x += v.x; s4.y += v.y; s4.z += v.z; s4.w += v.w;
    }
    float s = (s4.x + s4.y) + (s4.z + s4.w);
    #pragma unroll
    for (int off = 32; off > 0; off >>= 1)
        s += __shfl_xor(s, off);

    __shared__ float wsum[4];
    const int lane = threadIdx.x & 63, w = threadIdx.x >> 6;
    if (lane == 0) wsum[w] = s;
    __syncthreads();
    if (threadIdx.x == 0)
        out[0] = (wsum[0] + wsum[1] + wsum[2] + wsum[3]) * invB;
}

extern "C" void kernel_launch(void* const* d_in, const int* in_sizes, int n_in,
                              void* d_out, int out_size, void* d_ws, size_t ws_size,
                              hipStream_t stream) {
    const float* pred      = (const float*)d_in[0];
    const int*   label_rc  = (const int*)d_in[1];
    const float* label_box = (const float*)d_in[2];
    float*       out       = (float*)d_out;
    float*       partials  = (float*)d_ws;

    const int B = in_sizes[0] / 512;          // G*G*C = 8*8*8
    const int L = in_sizes[1] / (B * 2);      // labels per batch (16)
    const float invB = 1.0f / (float)B;

    const int blocks = (B + 3) / 4;           // one wave (64 lanes) per batch
    yolo_loss_kernel<<<blocks, 256, 0, stream>>>(
        pred, label_rc, label_box, partials, B, L);

    reduce_kernel<<<1, 256, 0, stream>>>(partials, out, blocks / 4, invB);
}